// Round 5
// baseline (1148.062 us; speedup 1.0000x reference)
//
#include <hip/hip_runtime.h>
#include <hip/hip_bf16.h>

// Problem constants
#define NF 32          // n_features
#define NCH 64         // n_channels
#define TRAW 16384     // raw samples
#define TPAD 16448     // TRAW + 64 (left reflect pad)
#define TP 4112        // TPAD / 4
#define TE 4104        // TP - 8  (after encoder MA, kernel size 9)
#define TD 4096        // TE - 8  (after decoder MA) == TRAW/4

// Workspace layout (floats)
#define OFF_SPAD   0u                     // [32][16448]
#define OFF_AMEAN  526336u                // [32][4112]
#define OFF_ACOV   657920u                // [4112][1024] t-major
#define OFF_XMEAN  4868608u               // [32][4104]
#define OFF_XCOV   4999936u               // [4104][1024] t-major
// reuse: AMEANT aliases AMEAN (consumed), ACOVT aliases ACOV (consumed)
#define OFF_AMEANT OFF_AMEAN              // [32][4096]
#define OFF_ACOVT  OFF_ACOV               // [4096][1024]

// ---------------------------------------------------------------------------
// 1) s_pad[f,t] = sum_c W_enc[f,c] * y_pad[c,t],  y_pad[c,t] = y[c, |t-64|]
__global__ void senc_kernel(const float* __restrict__ y,
                            const float* __restrict__ Wenc,
                            float* __restrict__ spad) {
    int t = blockIdx.x * 256 + threadIdx.x;
    int f = blockIdx.y;
    if (t >= TPAD) return;
    int tt = (t >= 64) ? (t - 64) : (64 - t);   // reflect pad
    float acc = 0.f;
#pragma unroll
    for (int c = 0; c < NCH; ++c)
        acc = fmaf(Wenc[f * NCH + c], y[c * TRAW + tt], acc);
    spad[f * TPAD + t] = acc;
}

// ---------------------------------------------------------------------------
// 2) per-t4 stats: a_mean[f,t4], a_cov[t4][c][s]  (8 t4 per block)
__global__ __launch_bounds__(256) void stats_kernel(const float* __restrict__ spad,
                                                    float* __restrict__ amean,
                                                    float* __restrict__ acov) {
    __shared__ float sab[32][33];   // padded (bank conflicts)
    __shared__ float mu[32][9];
    int tid = threadIdx.x;
    int t0 = blockIdx.x * 8;        // 514 blocks * 8 = 4112
#pragma unroll
    for (int i = 0; i < 4; ++i) {
        int idx = tid + 256 * i;    // 0..1023
        int f = idx >> 5, j = idx & 31;
        sab[f][j] = fabsf(spad[f * TPAD + t0 * 4 + j]);
    }
    __syncthreads();
    {
        int f = tid >> 3, tt = tid & 7;
        float m = 0.25f * (sab[f][tt * 4] + sab[f][tt * 4 + 1] +
                           sab[f][tt * 4 + 2] + sab[f][tt * 4 + 3]);
        mu[f][tt] = m;
        amean[f * TP + t0 + tt] = m;
    }
    __syncthreads();
    const float inv3 = 1.f / 3.f;
#pragma unroll
    for (int e = 0; e < 32; ++e) {
        int flat = e * 256 + tid;   // 0..8191
        int tt = flat >> 10, r = flat & 1023;
        int c = r >> 5, s = r & 31;
        float mc = mu[c][tt], ms = mu[s][tt];
        float acc = 0.f;
#pragma unroll
        for (int d = 0; d < 4; ++d)
            acc += (sab[c][tt * 4 + d] - mc) * (sab[s][tt * 4 + d] - ms);
        acov[(size_t)(t0 + tt) * 1024 + r] = acc * inv3;
    }
}

// ---------------------------------------------------------------------------
// 3/5) mean MA: out[c,t] = b[c] + in[c,t+8] + sum_{k<8,C} w[c,C,k]*in[C,t+k]
__global__ void mamean_kernel(const float* __restrict__ in, int instride,
                              const float* __restrict__ w,
                              const float* __restrict__ b,
                              float* __restrict__ outp, int Tout) {
    int t = blockIdx.x * 256 + threadIdx.x;
    int c = blockIdx.y;
    if (t >= Tout) return;
    float acc = b[c] + in[c * instride + t + 8];
    for (int C = 0; C < NF; ++C) {
#pragma unroll
        for (int k = 0; k < 8; ++k)
            acc = fmaf(w[(c * NF + C) * 8 + k], in[C * instride + t + k], acc);
    }
    outp[c * Tout + t] = acc;
}

// ---------------------------------------------------------------------------
// 4/6) cov MA v2: out_t[c][s] = scale * ( A_{t+8}[c][s] +
//        sum_{k<8} sum_C F[c][C][k] * (sum_S A_{t+k}[C][S] * F[s][S][k]) )
//  Barrier-free after fe staging: per-lane h-dot with wave-uniform float4 A
//  loads; fe read via b128 LDS broadcast. 8 waves/block, one t per wave.
__global__ __launch_bounds__(512) void macov_kernel(const float* __restrict__ Ain,
                                                    const float* __restrict__ maw,
                                                    const float* __restrict__ scale_ptr,
                                                    float* __restrict__ Aout,
                                                    int Tout) {
    __shared__ __align__(16) float fe[9 * 1024];  // fe[k*1024 + C*32 + c] = F[c][C][k]
    int tid = threadIdx.x;
#pragma unroll
    for (int i = 0; i < 18; ++i) {
        int idx = tid + 512 * i;     // 0..9215
        int k = idx >> 10, r = idx & 1023;
        int C = r >> 5, c = r & 31;
        fe[idx] = (k < 8) ? maw[(c * NF + C) * 8 + k] : (c == C ? 1.f : 0.f);
    }
    __syncthreads();
    int w = tid >> 6;                // wave id, 8 waves
    int l = tid & 63;
    int t = blockIdx.x * 8 + w;      // Tout divisible by 8 (4104=8*513, 4096=8*512)
    int hi = l >> 5, s = l & 31;     // lane owns rows c = hi*16+e, col s
    float acc[16];
#pragma unroll
    for (int e = 0; e < 16; ++e) acc[e] = 0.f;

    for (int k = 0; k < 8; ++k) {
        const float* fek = fe + (k << 10);
        float fsk[32];               // F[s][S][k] for this lane's s
#pragma unroll
        for (int S = 0; S < 32; ++S) fsk[S] = fek[S * 32 + s];
        const float* Arow = Ain + (size_t)(t + k) * 1024;
#pragma unroll 4
        for (int C = 0; C < 32; ++C) {
            const float4* Ar4 = (const float4*)(Arow + C * 32);  // wave-uniform
            float h0 = 0.f, h1 = 0.f, h2 = 0.f, h3 = 0.f;
#pragma unroll
            for (int j = 0; j < 8; j += 4) {
                float4 a0 = Ar4[j + 0], a1 = Ar4[j + 1], a2 = Ar4[j + 2], a3 = Ar4[j + 3];
                h0 = fmaf(a0.x, fsk[4 * j + 0], h0);  h0 = fmaf(a0.y, fsk[4 * j + 1], h0);
                h1 = fmaf(a0.z, fsk[4 * j + 2], h1);  h1 = fmaf(a0.w, fsk[4 * j + 3], h1);
                h0 = fmaf(a1.x, fsk[4 * j + 4], h0);  h0 = fmaf(a1.y, fsk[4 * j + 5], h0);
                h1 = fmaf(a1.z, fsk[4 * j + 6], h1);  h1 = fmaf(a1.w, fsk[4 * j + 7], h1);
                h2 = fmaf(a2.x, fsk[4 * j + 8], h2);  h2 = fmaf(a2.y, fsk[4 * j + 9], h2);
                h3 = fmaf(a2.z, fsk[4 * j + 10], h3); h3 = fmaf(a2.w, fsk[4 * j + 11], h3);
                h2 = fmaf(a3.x, fsk[4 * j + 12], h2); h2 = fmaf(a3.y, fsk[4 * j + 13], h2);
                h3 = fmaf(a3.z, fsk[4 * j + 14], h3); h3 = fmaf(a3.w, fsk[4 * j + 15], h3);
            }
            float h = (h0 + h1) + (h2 + h3);
            const float4* fr4 = (const float4*)(fek + C * 32 + hi * 16);  // b128 bcast
#pragma unroll
            for (int j = 0; j < 4; ++j) {
                float4 f = fr4[j];
                acc[4 * j + 0] = fmaf(f.x, h, acc[4 * j + 0]);
                acc[4 * j + 1] = fmaf(f.y, h, acc[4 * j + 1]);
                acc[4 * j + 2] = fmaf(f.z, h, acc[4 * j + 2]);
                acc[4 * j + 3] = fmaf(f.w, h, acc[4 * j + 3]);
            }
        }
    }
    // k = 8: identity term
    {
        const float* Arow = Ain + (size_t)(t + 8) * 1024;
#pragma unroll
        for (int e = 0; e < 16; ++e) acc[e] += Arow[(hi * 16 + e) * 32 + s];
    }
    float sc = scale_ptr ? *scale_ptr : 1.f;
    float* Orow = Aout + (size_t)t * 1024;
#pragma unroll
    for (int e = 0; e < 16; ++e) Orow[(hi * 16 + e) * 32 + s] = acc[e] * sc;
}

// ---------------------------------------------------------------------------
// 7) y_mean rows 0..63: out[o,t] = sum_f Wdec[o,f]*a_mean_t[f,t/4]*sgn(spad[f,t+64])
__global__ void ymean_kernel(const float* __restrict__ spad,
                             const float* __restrict__ ameant,
                             const float* __restrict__ Wdec,
                             float* __restrict__ out) {
    int t = blockIdx.x * 256 + threadIdx.x;   // < 16384
    int o = blockIdx.y;
    int t4 = t >> 2;
    float acc = 0.f;
#pragma unroll
    for (int f = 0; f < NF; ++f) {
        float sp = spad[f * TPAD + 64 + t];
        float sgn = (sp > 0.f) ? 1.f : (sp < 0.f ? -1.f : 0.f);
        acc = fmaf(Wdec[o * NF + f], ameant[f * TD + t4] * sgn, acc);
    }
    out[o * TRAW + t] = acc;
}

// ---------------------------------------------------------------------------
// 8) y_cov v2 rows 64..4159. Block owns 4 consecutive t4; writes full 64B lines.
//    LDS: W2 (8KB, row-major for b128 bcast) + B4 (32.9KB padded) = 40.9 KB.
#define B4S 2056   // padded per-t4 stride (floats): t4l*8224B -> +32B bank shift
__global__ __launch_bounds__(256) void ycov_kernel(const float* __restrict__ Acovt,
                                                   const float* __restrict__ Wdec,
                                                   float* __restrict__ out) {
    __shared__ __align__(16) float W2[64 * 32];   // W2[o*32+i] = Wdec[o][i]
    __shared__ __align__(16) float B4[4 * B4S];   // B4[t4l*B4S + o*32 + I]
    int tid = threadIdx.x;
    int T0 = blockIdx.x * 4;        // gridDim.x == 1024

#pragma unroll
    for (int i = 0; i < 8; ++i) {
        int idx = tid + 256 * i;    // 0..2047, coalesced
        W2[idx] = Wdec[idx];
    }
    __syncthreads();

    // B-stage: wave = one t4. B[t4][o][I] = sum_i Wdec[o][i] * A[t4][i][I]
    {
        int t4l = tid >> 6, I = tid & 31, half = (tid >> 5) & 1;
        const float* Arow = Acovt + (size_t)(T0 + t4l) * 1024;
        float areg[32];
#pragma unroll
        for (int i = 0; i < 32; ++i) areg[i] = Arow[i * 32 + I];  // coalesced
        float* Bb = B4 + t4l * B4S + I;
#pragma unroll 4
        for (int oj = 0; oj < 32; ++oj) {
            int o = half * 32 + oj;
            const float4* Wr = (const float4*)(W2 + o * 32);      // b128 bcast
            float a0 = 0.f, a1 = 0.f, a2 = 0.f, a3 = 0.f;
#pragma unroll
            for (int j = 0; j < 8; j += 4) {
                float4 w0 = Wr[j], w1 = Wr[j + 1], w2 = Wr[j + 2], w3 = Wr[j + 3];
                a0 = fmaf(w0.x, areg[4 * j + 0], a0);  a0 = fmaf(w0.y, areg[4 * j + 1], a0);
                a1 = fmaf(w0.z, areg[4 * j + 2], a1);  a1 = fmaf(w0.w, areg[4 * j + 3], a1);
                a0 = fmaf(w1.x, areg[4 * j + 4], a0);  a0 = fmaf(w1.y, areg[4 * j + 5], a0);
                a1 = fmaf(w1.z, areg[4 * j + 6], a1);  a1 = fmaf(w1.w, areg[4 * j + 7], a1);
                a2 = fmaf(w2.x, areg[4 * j + 8], a2);  a2 = fmaf(w2.y, areg[4 * j + 9], a2);
                a3 = fmaf(w2.z, areg[4 * j + 10], a3); a3 = fmaf(w2.w, areg[4 * j + 11], a3);
                a2 = fmaf(w3.x, areg[4 * j + 12], a2); a2 = fmaf(w3.y, areg[4 * j + 13], a2);
                a3 = fmaf(w3.z, areg[4 * j + 14], a3); a3 = fmaf(w3.w, areg[4 * j + 15], a3);
            }
            Bb[o * 32] = (a0 + a1) + (a2 + a3);
        }
    }
    __syncthreads();

    // M-stage: lane owns (O = tid>>2, t4l = tid&3); loops o. Full-line stores.
    {
        int O = tid >> 2, t4l = tid & 3;
        float4 wv[8];
#pragma unroll
        for (int j = 0; j < 8; ++j) wv[j] = ((const float4*)(Wdec + O * 32))[j];
        float4* out4 = (float4*)out;
        const float* Bbase = B4 + t4l * B4S;
#pragma unroll 2
        for (int o = 0; o < 64; ++o) {
            const float4* Br = (const float4*)(Bbase + o * 32);
            float a0 = 0.f, a1 = 0.f, a2 = 0.f, a3 = 0.f;
#pragma unroll
            for (int j = 0; j < 8; j += 4) {
                float4 b0 = Br[j], b1 = Br[j + 1], b2 = Br[j + 2], b3 = Br[j + 3];
                a0 = fmaf(b0.x, wv[j].x, a0);      a0 = fmaf(b0.y, wv[j].y, a0);
                a1 = fmaf(b0.z, wv[j].z, a1);      a1 = fmaf(b0.w, wv[j].w, a1);
                a0 = fmaf(b1.x, wv[j + 1].x, a0);  a0 = fmaf(b1.y, wv[j + 1].y, a0);
                a1 = fmaf(b1.z, wv[j + 1].z, a1);  a1 = fmaf(b1.w, wv[j + 1].w, a1);
                a2 = fmaf(b2.x, wv[j + 2].x, a2);  a2 = fmaf(b2.y, wv[j + 2].y, a2);
                a3 = fmaf(b2.z, wv[j + 2].z, a3);  a3 = fmaf(b2.w, wv[j + 2].w, a3);
                a2 = fmaf(b3.x, wv[j + 3].x, a2);  a2 = fmaf(b3.y, wv[j + 3].y, a2);
                a3 = fmaf(b3.z, wv[j + 3].z, a3);  a3 = fmaf(b3.w, wv[j + 3].w, a3);
            }
            float acc = (a0 + a1) + (a2 + a3);
            size_t r = 64 + o * 64 + O;       // output row
            out4[r * (TRAW / 4) + T0 + t4l] = make_float4(acc, acc, acc, acc);
        }
    }
}

// ---------------------------------------------------------------------------
extern "C" void kernel_launch(void* const* d_in, const int* in_sizes, int n_in,
                              void* d_out, int out_size, void* d_ws, size_t ws_size,
                              hipStream_t stream) {
    const float* y      = (const float*)d_in[0];
    const float* Wenc   = (const float*)d_in[1];
    const float* Wdec   = (const float*)d_in[2];
    const float* mawE   = (const float*)d_in[3];
    const float* mabE   = (const float*)d_in[4];
    const float* mawD   = (const float*)d_in[5];
    const float* mabD   = (const float*)d_in[6];
    const float* covsc  = (const float*)d_in[7];
    float* out = (float*)d_out;
    float* ws  = (float*)d_ws;

    float* spad   = ws + OFF_SPAD;
    float* amean  = ws + OFF_AMEAN;
    float* acov   = ws + OFF_ACOV;
    float* xmean  = ws + OFF_XMEAN;
    float* xcov   = ws + OFF_XCOV;
    float* ameant = ws + OFF_AMEANT;
    float* acovt  = ws + OFF_ACOVT;

    // 1) spatial encode + pad
    senc_kernel<<<dim3((TPAD + 255) / 256, NF), 256, 0, stream>>>(y, Wenc, spad);
    // 2) downsample stats
    stats_kernel<<<dim3(TP / 8), 256, 0, stream>>>(spad, amean, acov);
    // 3) encoder mean MA
    mamean_kernel<<<dim3((TE + 255) / 256, NF), 256, 0, stream>>>(amean, TP, mawE, mabE, xmean, TE);
    // 4) encoder cov MA (scaled by cov_scaler) — 8 t per block
    macov_kernel<<<dim3(TE / 8), 512, 0, stream>>>(acov, mawE, covsc, xcov, TE);
    // 5) decoder mean MA
    mamean_kernel<<<dim3((TD + 255) / 256, NF), 256, 0, stream>>>(xmean, TE, mawD, mabD, ameant, TD);
    // 6) decoder cov MA — 8 t per block
    macov_kernel<<<dim3(TD / 8), 512, 0, stream>>>(xcov, mawD, nullptr, acovt, TD);
    // 7) y_mean
    ymean_kernel<<<dim3(TRAW / 256, NCH), 256, 0, stream>>>(spad, ameant, Wdec, out);
    // 8) y_cov — 4 t4 per block
    ycov_kernel<<<dim3(TD / 4), 256, 0, stream>>>(acovt, Wdec, out);
}

// Round 6
// 819.058 us; speedup vs baseline: 1.4017x; 1.4017x over previous
//
#include <hip/hip_runtime.h>
#include <hip/hip_bf16.h>

// Problem constants
#define NF 32          // n_features
#define NCH 64         // n_channels
#define TRAW 16384     // raw samples
#define TPAD 16448     // TRAW + 64 (left reflect pad)
#define TP 4112        // TPAD / 4
#define TE 4104        // TP - 8  (after encoder MA, kernel size 9)
#define TD 4096        // TE - 8  (after decoder MA) == TRAW/4

// Workspace layout (floats)
#define OFF_SPAD   0u                     // [32][16448]
#define OFF_AMEAN  526336u                // [32][4112]
#define OFF_ACOV   657920u                // [4112][1024] t-major
#define OFF_XMEAN  4868608u               // [32][4104]
#define OFF_XCOV   4999936u               // [4104][1024] t-major
// reuse: AMEANT aliases AMEAN (consumed), ACOVT aliases ACOV (consumed)
#define OFF_AMEANT OFF_AMEAN              // [32][4096]
#define OFF_ACOVT  OFF_ACOV               // [4096][1024]

// ---------------------------------------------------------------------------
// 1) s_pad[f,t] = sum_c W_enc[f,c] * y_pad[c,t],  y_pad[c,t] = y[c, |t-64|]
__global__ void senc_kernel(const float* __restrict__ y,
                            const float* __restrict__ Wenc,
                            float* __restrict__ spad) {
    int t = blockIdx.x * 256 + threadIdx.x;
    int f = blockIdx.y;
    if (t >= TPAD) return;
    int tt = (t >= 64) ? (t - 64) : (64 - t);   // reflect pad
    float acc = 0.f;
#pragma unroll
    for (int c = 0; c < NCH; ++c)
        acc = fmaf(Wenc[f * NCH + c], y[c * TRAW + tt], acc);
    spad[f * TPAD + t] = acc;
}

// ---------------------------------------------------------------------------
// 2) per-t4 stats: a_mean[f,t4], a_cov[t4][c][s]  (8 t4 per block)
__global__ __launch_bounds__(256) void stats_kernel(const float* __restrict__ spad,
                                                    float* __restrict__ amean,
                                                    float* __restrict__ acov) {
    __shared__ float sab[32][33];   // padded (bank conflicts)
    __shared__ float mu[32][9];
    int tid = threadIdx.x;
    int t0 = blockIdx.x * 8;        // 514 blocks * 8 = 4112
#pragma unroll
    for (int i = 0; i < 4; ++i) {
        int idx = tid + 256 * i;    // 0..1023
        int f = idx >> 5, j = idx & 31;
        sab[f][j] = fabsf(spad[f * TPAD + t0 * 4 + j]);
    }
    __syncthreads();
    {
        int f = tid >> 3, tt = tid & 7;
        float m = 0.25f * (sab[f][tt * 4] + sab[f][tt * 4 + 1] +
                           sab[f][tt * 4 + 2] + sab[f][tt * 4 + 3]);
        mu[f][tt] = m;
        amean[f * TP + t0 + tt] = m;
    }
    __syncthreads();
    const float inv3 = 1.f / 3.f;
#pragma unroll
    for (int e = 0; e < 32; ++e) {
        int flat = e * 256 + tid;   // 0..8191
        int tt = flat >> 10, r = flat & 1023;
        int c = r >> 5, s = r & 31;
        float mc = mu[c][tt], ms = mu[s][tt];
        float acc = 0.f;
#pragma unroll
        for (int d = 0; d < 4; ++d)
            acc += (sab[c][tt * 4 + d] - mc) * (sab[s][tt * 4 + d] - ms);
        acov[(size_t)(t0 + tt) * 1024 + r] = acc * inv3;
    }
}

// ---------------------------------------------------------------------------
// 3/5) mean MA: out[c,t] = b[c] + in[c,t+8] + sum_{k<8,C} w[c,C,k]*in[C,t+k]
__global__ void mamean_kernel(const float* __restrict__ in, int instride,
                              const float* __restrict__ w,
                              const float* __restrict__ b,
                              float* __restrict__ outp, int Tout) {
    int t = blockIdx.x * 256 + threadIdx.x;
    int c = blockIdx.y;
    if (t >= Tout) return;
    float acc = b[c] + in[c * instride + t + 8];
    for (int C = 0; C < NF; ++C) {
#pragma unroll
        for (int k = 0; k < 8; ++k)
            acc = fmaf(w[(c * NF + C) * 8 + k], in[C * instride + t + k], acc);
    }
    outp[c * Tout + t] = acc;
}

// ---------------------------------------------------------------------------
// 4/6) cov MA v4: out_t[c][s] = scale*( A_{t+8}[c][s] +
//        sum_{k<8} sum_C F[c][C][k] * h_k[C][s] ),  h_k[C][s]=sum_S A_{t+k}[C][S]*F[s][S][k]
//  One wave per t, barrier-free k-loop. Half-wave hi owns C in [hi*16,hi*16+16);
//  partial out over its C-half accumulated for ALL c; one shfl_xor(32) merge at end.
//  A rows read from global (L1/L2 broadcast); fe in 32KB LDS feT[k][in][out].
__global__ __launch_bounds__(512, 4) void macov_kernel(const float* __restrict__ Ain,
                                                       const float* __restrict__ maw,
                                                       const float* __restrict__ scale_ptr,
                                                       float* __restrict__ Aout,
                                                       int Tout) {
    __shared__ __align__(16) float feT[8 * 1024];  // feT[k*1024 + in*32 + out] = filtr[out][in][k]
    int tid = threadIdx.x;
#pragma unroll
    for (int i = 0; i < 16; ++i) {
        int idx = tid + 512 * i;     // 0..8191
        int k = idx >> 10, r = idx & 1023;
        int IN = r >> 5, OUT = r & 31;
        feT[idx] = maw[(OUT * NF + IN) * 8 + k];
    }
    __syncthreads();
    int w = tid >> 6;                // wave id, 8 waves
    int l = tid & 63;
    int t = blockIdx.x * 8 + w;      // Tout divisible by 8 (4104, 4096)
    int hi = l >> 5, s = l & 31;
    int c0 = hi * 16;                // this half-wave's C range
    float acc[32];
#pragma unroll
    for (int c = 0; c < 32; ++c) acc[c] = 0.f;

    for (int k = 0; k < 8; ++k) {
        const float* fek = feT + (k << 10);
        float fsk[32];               // F[s][S][k] = fek[S*32 + s]
#pragma unroll
        for (int S = 0; S < 32; ++S) fsk[S] = fek[S * 32 + s];
        const float* Arow = Ain + (size_t)(t + k) * 1024 + c0 * 32;
#pragma unroll 2
        for (int Ci = 0; Ci < 16; ++Ci) {
            const float4* Ar4 = (const float4*)(Arow + Ci * 32);  // 2 addrs/wave (bcast)
            float4 a0 = Ar4[0], a1 = Ar4[1], a2 = Ar4[2], a3 = Ar4[3];
            float4 a4 = Ar4[4], a5 = Ar4[5], a6 = Ar4[6], a7 = Ar4[7];
            float h0 = 0.f, h1 = 0.f, h2 = 0.f, h3 = 0.f;
            h0 = fmaf(a0.x, fsk[0],  h0); h0 = fmaf(a0.y, fsk[1],  h0);
            h1 = fmaf(a0.z, fsk[2],  h1); h1 = fmaf(a0.w, fsk[3],  h1);
            h0 = fmaf(a1.x, fsk[4],  h0); h0 = fmaf(a1.y, fsk[5],  h0);
            h1 = fmaf(a1.z, fsk[6],  h1); h1 = fmaf(a1.w, fsk[7],  h1);
            h2 = fmaf(a2.x, fsk[8],  h2); h2 = fmaf(a2.y, fsk[9],  h2);
            h3 = fmaf(a2.z, fsk[10], h3); h3 = fmaf(a2.w, fsk[11], h3);
            h2 = fmaf(a3.x, fsk[12], h2); h2 = fmaf(a3.y, fsk[13], h2);
            h3 = fmaf(a3.z, fsk[14], h3); h3 = fmaf(a3.w, fsk[15], h3);
            h0 = fmaf(a4.x, fsk[16], h0); h0 = fmaf(a4.y, fsk[17], h0);
            h1 = fmaf(a4.z, fsk[18], h1); h1 = fmaf(a4.w, fsk[19], h1);
            h0 = fmaf(a5.x, fsk[20], h0); h0 = fmaf(a5.y, fsk[21], h0);
            h1 = fmaf(a5.z, fsk[22], h1); h1 = fmaf(a5.w, fsk[23], h1);
            h2 = fmaf(a6.x, fsk[24], h2); h2 = fmaf(a6.y, fsk[25], h2);
            h3 = fmaf(a6.z, fsk[26], h3); h3 = fmaf(a6.w, fsk[27], h3);
            h2 = fmaf(a7.x, fsk[28], h2); h2 = fmaf(a7.y, fsk[29], h2);
            h3 = fmaf(a7.z, fsk[30], h3); h3 = fmaf(a7.w, fsk[31], h3);
            float h = (h0 + h1) + (h2 + h3);
            // out[c] += F[c][C]*h for all c; F[c][C] = fek[(c0+Ci)*32 + c]
            const float4* fr4 = (const float4*)(fek + (c0 + Ci) * 32);
#pragma unroll
            for (int j = 0; j < 8; ++j) {
                float4 f = fr4[j];
                acc[4 * j + 0] = fmaf(f.x, h, acc[4 * j + 0]);
                acc[4 * j + 1] = fmaf(f.y, h, acc[4 * j + 1]);
                acc[4 * j + 2] = fmaf(f.z, h, acc[4 * j + 2]);
                acc[4 * j + 3] = fmaf(f.w, h, acc[4 * j + 3]);
            }
        }
    }
    // merge the two C-half partials (lane l <-> l^32 have same s)
#pragma unroll
    for (int c = 0; c < 32; ++c) acc[c] += __shfl_xor(acc[c], 32);
    // identity (k=8) + scale + store; lane stores rows c in its half
    float sc = scale_ptr ? *scale_ptr : 1.f;
    const float* A8 = Ain + (size_t)(t + 8) * 1024;
    float* Orow = Aout + (size_t)t * 1024;
#pragma unroll
    for (int e = 0; e < 16; ++e) {
        int c = c0 + e;
        Orow[c * 32 + s] = (acc[c] + A8[c * 32 + s]) * sc;
    }
}

// ---------------------------------------------------------------------------
// 7) y_mean rows 0..63: out[o,t] = sum_f Wdec[o,f]*a_mean_t[f,t/4]*sgn(spad[f,t+64])
__global__ void ymean_kernel(const float* __restrict__ spad,
                             const float* __restrict__ ameant,
                             const float* __restrict__ Wdec,
                             float* __restrict__ out) {
    int t = blockIdx.x * 256 + threadIdx.x;   // < 16384
    int o = blockIdx.y;
    int t4 = t >> 2;
    float acc = 0.f;
#pragma unroll
    for (int f = 0; f < NF; ++f) {
        float sp = spad[f * TPAD + 64 + t];
        float sgn = (sp > 0.f) ? 1.f : (sp < 0.f ? -1.f : 0.f);
        acc = fmaf(Wdec[o * NF + f], ameant[f * TD + t4] * sgn, acc);
    }
    out[o * TRAW + t] = acc;
}

// ---------------------------------------------------------------------------
// 8) y_cov v2 rows 64..4159. Block owns 4 consecutive t4; writes full 64B lines.
//    LDS: W2 (8KB, row-major for b128 bcast) + B4 (32.9KB padded) = 40.9 KB.
#define B4S 2056   // padded per-t4 stride (floats)
__global__ __launch_bounds__(256) void ycov_kernel(const float* __restrict__ Acovt,
                                                   const float* __restrict__ Wdec,
                                                   float* __restrict__ out) {
    __shared__ __align__(16) float W2[64 * 32];   // W2[o*32+i] = Wdec[o][i]
    __shared__ __align__(16) float B4[4 * B4S];   // B4[t4l*B4S + o*32 + I]
    int tid = threadIdx.x;
    int T0 = blockIdx.x * 4;        // gridDim.x == 1024

#pragma unroll
    for (int i = 0; i < 8; ++i) {
        int idx = tid + 256 * i;    // 0..2047, coalesced
        W2[idx] = Wdec[idx];
    }
    __syncthreads();

    // B-stage: wave = one t4. B[t4][o][I] = sum_i Wdec[o][i] * A[t4][i][I]
    {
        int t4l = tid >> 6, I = tid & 31, half = (tid >> 5) & 1;
        const float* Arow = Acovt + (size_t)(T0 + t4l) * 1024;
        float areg[32];
#pragma unroll
        for (int i = 0; i < 32; ++i) areg[i] = Arow[i * 32 + I];  // coalesced
        float* Bb = B4 + t4l * B4S + I;
#pragma unroll 4
        for (int oj = 0; oj < 32; ++oj) {
            int o = half * 32 + oj;
            const float4* Wr = (const float4*)(W2 + o * 32);      // b128 bcast
            float a0 = 0.f, a1 = 0.f, a2 = 0.f, a3 = 0.f;
#pragma unroll
            for (int j = 0; j < 8; j += 4) {
                float4 w0 = Wr[j], w1 = Wr[j + 1], w2 = Wr[j + 2], w3 = Wr[j + 3];
                a0 = fmaf(w0.x, areg[4 * j + 0], a0);  a0 = fmaf(w0.y, areg[4 * j + 1], a0);
                a1 = fmaf(w0.z, areg[4 * j + 2], a1);  a1 = fmaf(w0.w, areg[4 * j + 3], a1);
                a0 = fmaf(w1.x, areg[4 * j + 4], a0);  a0 = fmaf(w1.y, areg[4 * j + 5], a0);
                a1 = fmaf(w1.z, areg[4 * j + 6], a1);  a1 = fmaf(w1.w, areg[4 * j + 7], a1);
                a2 = fmaf(w2.x, areg[4 * j + 8], a2);  a2 = fmaf(w2.y, areg[4 * j + 9], a2);
                a3 = fmaf(w2.z, areg[4 * j + 10], a3); a3 = fmaf(w2.w, areg[4 * j + 11], a3);
                a2 = fmaf(w3.x, areg[4 * j + 12], a2); a2 = fmaf(w3.y, areg[4 * j + 13], a2);
                a3 = fmaf(w3.z, areg[4 * j + 14], a3); a3 = fmaf(w3.w, areg[4 * j + 15], a3);
            }
            Bb[o * 32] = (a0 + a1) + (a2 + a3);
        }
    }
    __syncthreads();

    // M-stage: lane owns (O = tid>>2, t4l = tid&3); loops o. Full-line stores.
    {
        int O = tid >> 2, t4l = tid & 3;
        float4 wv[8];
#pragma unroll
        for (int j = 0; j < 8; ++j) wv[j] = ((const float4*)(Wdec + O * 32))[j];
        float4* out4 = (float4*)out;
        const float* Bbase = B4 + t4l * B4S;
#pragma unroll 2
        for (int o = 0; o < 64; ++o) {
            const float4* Br = (const float4*)(Bbase + o * 32);
            float a0 = 0.f, a1 = 0.f, a2 = 0.f, a3 = 0.f;
#pragma unroll
            for (int j = 0; j < 8; j += 4) {
                float4 b0 = Br[j], b1 = Br[j + 1], b2 = Br[j + 2], b3 = Br[j + 3];
                a0 = fmaf(b0.x, wv[j].x, a0);      a0 = fmaf(b0.y, wv[j].y, a0);
                a1 = fmaf(b0.z, wv[j].z, a1);      a1 = fmaf(b0.w, wv[j].w, a1);
                a0 = fmaf(b1.x, wv[j + 1].x, a0);  a0 = fmaf(b1.y, wv[j + 1].y, a0);
                a1 = fmaf(b1.z, wv[j + 1].z, a1);  a1 = fmaf(b1.w, wv[j + 1].w, a1);
                a2 = fmaf(b2.x, wv[j + 2].x, a2);  a2 = fmaf(b2.y, wv[j + 2].y, a2);
                a3 = fmaf(b2.z, wv[j + 2].z, a3);  a3 = fmaf(b2.w, wv[j + 2].w, a3);
                a2 = fmaf(b3.x, wv[j + 3].x, a2);  a2 = fmaf(b3.y, wv[j + 3].y, a2);
                a3 = fmaf(b3.z, wv[j + 3].z, a3);  a3 = fmaf(b3.w, wv[j + 3].w, a3);
            }
            float acc = (a0 + a1) + (a2 + a3);
            size_t r = 64 + o * 64 + O;       // output row
            out4[r * (TRAW / 4) + T0 + t4l] = make_float4(acc, acc, acc, acc);
        }
    }
}

// ---------------------------------------------------------------------------
extern "C" void kernel_launch(void* const* d_in, const int* in_sizes, int n_in,
                              void* d_out, int out_size, void* d_ws, size_t ws_size,
                              hipStream_t stream) {
    const float* y      = (const float*)d_in[0];
    const float* Wenc   = (const float*)d_in[1];
    const float* Wdec   = (const float*)d_in[2];
    const float* mawE   = (const float*)d_in[3];
    const float* mabE   = (const float*)d_in[4];
    const float* mawD   = (const float*)d_in[5];
    const float* mabD   = (const float*)d_in[6];
    const float* covsc  = (const float*)d_in[7];
    float* out = (float*)d_out;
    float* ws  = (float*)d_ws;

    float* spad   = ws + OFF_SPAD;
    float* amean  = ws + OFF_AMEAN;
    float* acov   = ws + OFF_ACOV;
    float* xmean  = ws + OFF_XMEAN;
    float* xcov   = ws + OFF_XCOV;
    float* ameant = ws + OFF_AMEANT;
    float* acovt  = ws + OFF_ACOVT;

    // 1) spatial encode + pad
    senc_kernel<<<dim3((TPAD + 255) / 256, NF), 256, 0, stream>>>(y, Wenc, spad);
    // 2) downsample stats
    stats_kernel<<<dim3(TP / 8), 256, 0, stream>>>(spad, amean, acov);
    // 3) encoder mean MA
    mamean_kernel<<<dim3((TE + 255) / 256, NF), 256, 0, stream>>>(amean, TP, mawE, mabE, xmean, TE);
    // 4) encoder cov MA (scaled by cov_scaler) — 8 t per block
    macov_kernel<<<dim3(TE / 8), 512, 0, stream>>>(acov, mawE, covsc, xcov, TE);
    // 5) decoder mean MA
    mamean_kernel<<<dim3((TD + 255) / 256, NF), 256, 0, stream>>>(xmean, TE, mawD, mabD, ameant, TD);
    // 6) decoder cov MA — 8 t per block
    macov_kernel<<<dim3(TD / 8), 512, 0, stream>>>(xcov, mawD, nullptr, acovt, TD);
    // 7) y_mean
    ymean_kernel<<<dim3(TRAW / 256, NCH), 256, 0, stream>>>(spad, ameant, Wdec, out);
    // 8) y_cov — 4 t4 per block
    ycov_kernel<<<dim3(TD / 4), 256, 0, stream>>>(acovt, Wdec, out);
}

// Round 7
// 628.518 us; speedup vs baseline: 1.8266x; 1.3032x over previous
//
#include <hip/hip_runtime.h>
#include <hip/hip_bf16.h>

// Problem constants
#define NF 32          // n_features
#define NCH 64         // n_channels
#define TRAW 16384     // raw samples
#define TPAD 16448     // TRAW + 64 (left reflect pad)
#define TP 4112        // TPAD / 4
#define TE 4104        // TP - 8  (after encoder MA, kernel size 9)
#define TD 4096        // TE - 8  (after decoder MA) == TRAW/4

// Workspace layout (floats)
#define OFF_SPAD   0u                     // [32][16448]
#define OFF_AMEAN  526336u                // [32][4112]
#define OFF_ACOV   657920u                // [4112][1024] t-major
#define OFF_XMEAN  4868608u               // [32][4104]
#define OFF_XCOV   4999936u               // [4104][1024] t-major
// reuse: AMEANT aliases AMEAN (consumed), ACOVT aliases ACOV (consumed)
#define OFF_AMEANT OFF_AMEAN              // [32][4096]
#define OFF_ACOVT  OFF_ACOV               // [4096][1024]

// ---------------------------------------------------------------------------
// 1) s_pad[f,t] = sum_c W_enc[f,c] * y_pad[c,t],  y_pad[c,t] = y[c, |t-64|]
__global__ void senc_kernel(const float* __restrict__ y,
                            const float* __restrict__ Wenc,
                            float* __restrict__ spad) {
    int t = blockIdx.x * 256 + threadIdx.x;
    int f = blockIdx.y;
    if (t >= TPAD) return;
    int tt = (t >= 64) ? (t - 64) : (64 - t);   // reflect pad
    float acc = 0.f;
#pragma unroll
    for (int c = 0; c < NCH; ++c)
        acc = fmaf(Wenc[f * NCH + c], y[c * TRAW + tt], acc);
    spad[f * TPAD + t] = acc;
}

// ---------------------------------------------------------------------------
// 2) per-t4 stats: a_mean[f,t4], a_cov[t4][c][s]  (8 t4 per block)
__global__ __launch_bounds__(256) void stats_kernel(const float* __restrict__ spad,
                                                    float* __restrict__ amean,
                                                    float* __restrict__ acov) {
    __shared__ float sab[32][33];   // padded (bank conflicts)
    __shared__ float mu[32][9];
    int tid = threadIdx.x;
    int t0 = blockIdx.x * 8;        // 514 blocks * 8 = 4112
#pragma unroll
    for (int i = 0; i < 4; ++i) {
        int idx = tid + 256 * i;    // 0..1023
        int f = idx >> 5, j = idx & 31;
        sab[f][j] = fabsf(spad[f * TPAD + t0 * 4 + j]);
    }
    __syncthreads();
    {
        int f = tid >> 3, tt = tid & 7;
        float m = 0.25f * (sab[f][tt * 4] + sab[f][tt * 4 + 1] +
                           sab[f][tt * 4 + 2] + sab[f][tt * 4 + 3]);
        mu[f][tt] = m;
        amean[f * TP + t0 + tt] = m;
    }
    __syncthreads();
    const float inv3 = 1.f / 3.f;
#pragma unroll
    for (int e = 0; e < 32; ++e) {
        int flat = e * 256 + tid;   // 0..8191
        int tt = flat >> 10, r = flat & 1023;
        int c = r >> 5, s = r & 31;
        float mc = mu[c][tt], ms = mu[s][tt];
        float acc = 0.f;
#pragma unroll
        for (int d = 0; d < 4; ++d)
            acc += (sab[c][tt * 4 + d] - mc) * (sab[s][tt * 4 + d] - ms);
        acov[(size_t)(t0 + tt) * 1024 + r] = acc * inv3;
    }
}

// ---------------------------------------------------------------------------
// 3/5) mean MA: out[c,t] = b[c] + in[c,t+8] + sum_{k<8,C} w[c,C,k]*in[C,t+k]
__global__ void mamean_kernel(const float* __restrict__ in, int instride,
                              const float* __restrict__ w,
                              const float* __restrict__ b,
                              float* __restrict__ outp, int Tout) {
    int t = blockIdx.x * 256 + threadIdx.x;
    int c = blockIdx.y;
    if (t >= Tout) return;
    float acc = b[c] + in[c * instride + t + 8];
    for (int C = 0; C < NF; ++C) {
#pragma unroll
        for (int k = 0; k < 8; ++k)
            acc = fmaf(w[(c * NF + C) * 8 + k], in[C * instride + t + k], acc);
    }
    outp[c * Tout + t] = acc;
}

// ---------------------------------------------------------------------------
// 4/6) cov MA v5: out_t[c][s] = scale*( A_{t+8}[c][s] +
//        sum_{k<8} sum_C F[c][C][k] * h_k[C][s] ), h_k[C][s]=sum_S A_{t+k}[C][S]*F[s][S][k]
//  Block = 256 thr / 4 waves / 4 t. A rows t0..t0+11 staged ONCE in LDS
//  (coalesced, latency-parallel); compute loop is pure LDS-broadcast + FMA.
//  Half-wave hi owns C in [hi*16, hi*16+16); partial out accumulated for ALL c;
//  one shfl_xor(32) merge at the end. LDS 80KB -> 2 blocks/CU.
__global__ __launch_bounds__(256, 2) void macov_kernel(const float* __restrict__ Ain,
                                                       const float* __restrict__ maw,
                                                       const float* __restrict__ scale_ptr,
                                                       float* __restrict__ Aout,
                                                       int Tout) {
    __shared__ __align__(16) float feT[8 * 1024];    // feT[k*1024 + in*32 + out] = F[out][in][k]
    __shared__ __align__(16) float Asub[12 * 1024];  // rows t0..t0+11
    int tid = threadIdx.x;
    int t0 = blockIdx.x * 4;         // Tout divisible by 4 (4104, 4096)

    // stage A rows t0..t0+11 (3072 float4, coalesced, all independent)
    {
        const float4* src = (const float4*)(Ain + (size_t)t0 * 1024);
        float4* dst = (float4*)Asub;
#pragma unroll
        for (int i = 0; i < 12; ++i) dst[tid + 256 * i] = src[tid + 256 * i];
    }
    // stage feT
#pragma unroll
    for (int i = 0; i < 32; ++i) {
        int idx = tid + 256 * i;     // 0..8191
        int k = idx >> 10, r = idx & 1023;
        int IN = r >> 5, OUT = r & 31;
        feT[idx] = maw[(OUT * NF + IN) * 8 + k];
    }
    __syncthreads();

    int w = tid >> 6;                // wave id, 4 waves
    int l = tid & 63;
    int t = t0 + w;
    int hi = l >> 5, s = l & 31;
    int c0 = hi * 16;                // this half-wave's C range
    float acc[32];
#pragma unroll
    for (int c = 0; c < 32; ++c) acc[c] = 0.f;

    for (int k = 0; k < 8; ++k) {
        const float* fek = feT + (k << 10);
        float fsk[32];               // F[s][S][k] = fek[S*32 + s]
#pragma unroll
        for (int S = 0; S < 32; ++S) fsk[S] = fek[S * 32 + s];
        const float* Arow = Asub + (w + k) * 1024 + c0 * 32;
#pragma unroll 2
        for (int Ci = 0; Ci < 16; ++Ci) {
            const float4* Ar4 = (const float4*)(Arow + Ci * 32);  // LDS bcast per half
            float4 a0 = Ar4[0], a1 = Ar4[1], a2 = Ar4[2], a3 = Ar4[3];
            float4 a4 = Ar4[4], a5 = Ar4[5], a6 = Ar4[6], a7 = Ar4[7];
            float h0 = 0.f, h1 = 0.f, h2 = 0.f, h3 = 0.f;
            h0 = fmaf(a0.x, fsk[0],  h0); h0 = fmaf(a0.y, fsk[1],  h0);
            h1 = fmaf(a0.z, fsk[2],  h1); h1 = fmaf(a0.w, fsk[3],  h1);
            h0 = fmaf(a1.x, fsk[4],  h0); h0 = fmaf(a1.y, fsk[5],  h0);
            h1 = fmaf(a1.z, fsk[6],  h1); h1 = fmaf(a1.w, fsk[7],  h1);
            h2 = fmaf(a2.x, fsk[8],  h2); h2 = fmaf(a2.y, fsk[9],  h2);
            h3 = fmaf(a2.z, fsk[10], h3); h3 = fmaf(a2.w, fsk[11], h3);
            h2 = fmaf(a3.x, fsk[12], h2); h2 = fmaf(a3.y, fsk[13], h2);
            h3 = fmaf(a3.z, fsk[14], h3); h3 = fmaf(a3.w, fsk[15], h3);
            h0 = fmaf(a4.x, fsk[16], h0); h0 = fmaf(a4.y, fsk[17], h0);
            h1 = fmaf(a4.z, fsk[18], h1); h1 = fmaf(a4.w, fsk[19], h1);
            h0 = fmaf(a5.x, fsk[20], h0); h0 = fmaf(a5.y, fsk[21], h0);
            h1 = fmaf(a5.z, fsk[22], h1); h1 = fmaf(a5.w, fsk[23], h1);
            h2 = fmaf(a6.x, fsk[24], h2); h2 = fmaf(a6.y, fsk[25], h2);
            h3 = fmaf(a6.z, fsk[26], h3); h3 = fmaf(a6.w, fsk[27], h3);
            h2 = fmaf(a7.x, fsk[28], h2); h2 = fmaf(a7.y, fsk[29], h2);
            h3 = fmaf(a7.z, fsk[30], h3); h3 = fmaf(a7.w, fsk[31], h3);
            float h = (h0 + h1) + (h2 + h3);
            // out[c] += F[c][C]*h for all c; F[c][C] = fek[(c0+Ci)*32 + c]
            const float4* fr4 = (const float4*)(fek + (c0 + Ci) * 32);
#pragma unroll
            for (int j = 0; j < 8; ++j) {
                float4 f = fr4[j];
                acc[4 * j + 0] = fmaf(f.x, h, acc[4 * j + 0]);
                acc[4 * j + 1] = fmaf(f.y, h, acc[4 * j + 1]);
                acc[4 * j + 2] = fmaf(f.z, h, acc[4 * j + 2]);
                acc[4 * j + 3] = fmaf(f.w, h, acc[4 * j + 3]);
            }
        }
    }
    // merge the two C-half partials (lane l <-> l^32 have same s)
#pragma unroll
    for (int c = 0; c < 32; ++c) acc[c] += __shfl_xor(acc[c], 32);
    // identity (k=8, from LDS) + scale + store; lane stores rows c in its half
    float sc = scale_ptr ? *scale_ptr : 1.f;
    const float* A8 = Asub + (w + 8) * 1024;
    float* Orow = Aout + (size_t)t * 1024;
#pragma unroll
    for (int e = 0; e < 16; ++e) {
        int c = c0 + e;
        Orow[c * 32 + s] = (acc[c] + A8[c * 32 + s]) * sc;
    }
}

// ---------------------------------------------------------------------------
// 7) y_mean rows 0..63: out[o,t] = sum_f Wdec[o,f]*a_mean_t[f,t/4]*sgn(spad[f,t+64])
__global__ void ymean_kernel(const float* __restrict__ spad,
                             const float* __restrict__ ameant,
                             const float* __restrict__ Wdec,
                             float* __restrict__ out) {
    int t = blockIdx.x * 256 + threadIdx.x;   // < 16384
    int o = blockIdx.y;
    int t4 = t >> 2;
    float acc = 0.f;
#pragma unroll
    for (int f = 0; f < NF; ++f) {
        float sp = spad[f * TPAD + 64 + t];
        float sgn = (sp > 0.f) ? 1.f : (sp < 0.f ? -1.f : 0.f);
        acc = fmaf(Wdec[o * NF + f], ameant[f * TD + t4] * sgn, acc);
    }
    out[o * TRAW + t] = acc;
}

// ---------------------------------------------------------------------------
// 8) y_cov v2 rows 64..4159. Block owns 4 consecutive t4; writes full 64B lines.
//    LDS: W2 (8KB, row-major for b128 bcast) + B4 (32.9KB padded) = 40.9 KB.
#define B4S 2056   // padded per-t4 stride (floats)
__global__ __launch_bounds__(256) void ycov_kernel(const float* __restrict__ Acovt,
                                                   const float* __restrict__ Wdec,
                                                   float* __restrict__ out) {
    __shared__ __align__(16) float W2[64 * 32];   // W2[o*32+i] = Wdec[o][i]
    __shared__ __align__(16) float B4[4 * B4S];   // B4[t4l*B4S + o*32 + I]
    int tid = threadIdx.x;
    int T0 = blockIdx.x * 4;        // gridDim.x == 1024

#pragma unroll
    for (int i = 0; i < 8; ++i) {
        int idx = tid + 256 * i;    // 0..2047, coalesced
        W2[idx] = Wdec[idx];
    }
    __syncthreads();

    // B-stage: wave = one t4. B[t4][o][I] = sum_i Wdec[o][i] * A[t4][i][I]
    {
        int t4l = tid >> 6, I = tid & 31, half = (tid >> 5) & 1;
        const float* Arow = Acovt + (size_t)(T0 + t4l) * 1024;
        float areg[32];
#pragma unroll
        for (int i = 0; i < 32; ++i) areg[i] = Arow[i * 32 + I];  // coalesced
        float* Bb = B4 + t4l * B4S + I;
#pragma unroll 4
        for (int oj = 0; oj < 32; ++oj) {
            int o = half * 32 + oj;
            const float4* Wr = (const float4*)(W2 + o * 32);      // b128 bcast
            float a0 = 0.f, a1 = 0.f, a2 = 0.f, a3 = 0.f;
#pragma unroll
            for (int j = 0; j < 8; j += 4) {
                float4 w0 = Wr[j], w1 = Wr[j + 1], w2 = Wr[j + 2], w3 = Wr[j + 3];
                a0 = fmaf(w0.x, areg[4 * j + 0], a0);  a0 = fmaf(w0.y, areg[4 * j + 1], a0);
                a1 = fmaf(w0.z, areg[4 * j + 2], a1);  a1 = fmaf(w0.w, areg[4 * j + 3], a1);
                a0 = fmaf(w1.x, areg[4 * j + 4], a0);  a0 = fmaf(w1.y, areg[4 * j + 5], a0);
                a1 = fmaf(w1.z, areg[4 * j + 6], a1);  a1 = fmaf(w1.w, areg[4 * j + 7], a1);
                a2 = fmaf(w2.x, areg[4 * j + 8], a2);  a2 = fmaf(w2.y, areg[4 * j + 9], a2);
                a3 = fmaf(w2.z, areg[4 * j + 10], a3); a3 = fmaf(w2.w, areg[4 * j + 11], a3);
                a2 = fmaf(w3.x, areg[4 * j + 12], a2); a2 = fmaf(w3.y, areg[4 * j + 13], a2);
                a3 = fmaf(w3.z, areg[4 * j + 14], a3); a3 = fmaf(w3.w, areg[4 * j + 15], a3);
            }
            Bb[o * 32] = (a0 + a1) + (a2 + a3);
        }
    }
    __syncthreads();

    // M-stage: lane owns (O = tid>>2, t4l = tid&3); loops o. Full-line stores.
    {
        int O = tid >> 2, t4l = tid & 3;
        float4 wv[8];
#pragma unroll
        for (int j = 0; j < 8; ++j) wv[j] = ((const float4*)(Wdec + O * 32))[j];
        float4* out4 = (float4*)out;
        const float* Bbase = B4 + t4l * B4S;
#pragma unroll 2
        for (int o = 0; o < 64; ++o) {
            const float4* Br = (const float4*)(Bbase + o * 32);
            float a0 = 0.f, a1 = 0.f, a2 = 0.f, a3 = 0.f;
#pragma unroll
            for (int j = 0; j < 8; j += 4) {
                float4 b0 = Br[j], b1 = Br[j + 1], b2 = Br[j + 2], b3 = Br[j + 3];
                a0 = fmaf(b0.x, wv[j].x, a0);      a0 = fmaf(b0.y, wv[j].y, a0);
                a1 = fmaf(b0.z, wv[j].z, a1);      a1 = fmaf(b0.w, wv[j].w, a1);
                a0 = fmaf(b1.x, wv[j + 1].x, a0);  a0 = fmaf(b1.y, wv[j + 1].y, a0);
                a1 = fmaf(b1.z, wv[j + 1].z, a1);  a1 = fmaf(b1.w, wv[j + 1].w, a1);
                a2 = fmaf(b2.x, wv[j + 2].x, a2);  a2 = fmaf(b2.y, wv[j + 2].y, a2);
                a3 = fmaf(b2.z, wv[j + 2].z, a3);  a3 = fmaf(b2.w, wv[j + 2].w, a3);
                a2 = fmaf(b3.x, wv[j + 3].x, a2);  a2 = fmaf(b3.y, wv[j + 3].y, a2);
                a3 = fmaf(b3.z, wv[j + 3].z, a3);  a3 = fmaf(b3.w, wv[j + 3].w, a3);
            }
            float acc = (a0 + a1) + (a2 + a3);
            size_t r = 64 + o * 64 + O;       // output row
            out4[r * (TRAW / 4) + T0 + t4l] = make_float4(acc, acc, acc, acc);
        }
    }
}

// ---------------------------------------------------------------------------
extern "C" void kernel_launch(void* const* d_in, const int* in_sizes, int n_in,
                              void* d_out, int out_size, void* d_ws, size_t ws_size,
                              hipStream_t stream) {
    const float* y      = (const float*)d_in[0];
    const float* Wenc   = (const float*)d_in[1];
    const float* Wdec   = (const float*)d_in[2];
    const float* mawE   = (const float*)d_in[3];
    const float* mabE   = (const float*)d_in[4];
    const float* mawD   = (const float*)d_in[5];
    const float* mabD   = (const float*)d_in[6];
    const float* covsc  = (const float*)d_in[7];
    float* out = (float*)d_out;
    float* ws  = (float*)d_ws;

    float* spad   = ws + OFF_SPAD;
    float* amean  = ws + OFF_AMEAN;
    float* acov   = ws + OFF_ACOV;
    float* xmean  = ws + OFF_XMEAN;
    float* xcov   = ws + OFF_XCOV;
    float* ameant = ws + OFF_AMEANT;
    float* acovt  = ws + OFF_ACOVT;

    // 1) spatial encode + pad
    senc_kernel<<<dim3((TPAD + 255) / 256, NF), 256, 0, stream>>>(y, Wenc, spad);
    // 2) downsample stats
    stats_kernel<<<dim3(TP / 8), 256, 0, stream>>>(spad, amean, acov);
    // 3) encoder mean MA
    mamean_kernel<<<dim3((TE + 255) / 256, NF), 256, 0, stream>>>(amean, TP, mawE, mabE, xmean, TE);
    // 4) encoder cov MA (scaled by cov_scaler) — 4 t per block
    macov_kernel<<<dim3(TE / 4), 256, 0, stream>>>(acov, mawE, covsc, xcov, TE);
    // 5) decoder mean MA
    mamean_kernel<<<dim3((TD + 255) / 256, NF), 256, 0, stream>>>(xmean, TE, mawD, mabD, ameant, TD);
    // 6) decoder cov MA — 4 t per block
    macov_kernel<<<dim3(TD / 4), 256, 0, stream>>>(xcov, mawD, nullptr, acovt, TD);
    // 7) y_mean
    ymean_kernel<<<dim3(TRAW / 256, NCH), 256, 0, stream>>>(spad, ameant, Wdec, out);
    // 8) y_cov — 4 t4 per block
    ycov_kernel<<<dim3(TD / 4), 256, 0, stream>>>(acovt, Wdec, out);
}